// Round 1
// 762.762 us; speedup vs baseline: 1.0485x; 1.0485x over previous
//
#include <hip/hip_runtime.h>
#include <hip/hip_bf16.h>

// Problem: B=32, S=1024, D=1024, dm=1024, 16 heads x 64
#define DM 1024
#define NB 32

typedef __bf16 bf16_t;
typedef __attribute__((ext_vector_type(8))) __bf16 bf16x8;
typedef __attribute__((ext_vector_type(4))) float  f32x4;

// address-space typedefs for global_load_lds
typedef __attribute__((address_space(1))) void gas_void;
typedef __attribute__((address_space(3))) void las_void;

__device__ __forceinline__ void async_lds16(const bf16_t* g, bf16_t* l) {
    // 16B/lane direct global->LDS DMA. LDS dest must be wave-uniform base +
    // lane*16 (it is: lds_byte = ch*16, ch = waveBase + lane).
    __builtin_amdgcn_global_load_lds((gas_void*)g, (las_void*)l, 16, 0, 0);
}

__device__ inline float bf2f(bf16_t v) {
    union { unsigned short s; __bf16 b; } u; u.b = v;
    union { unsigned int i; float f; } w; w.i = ((unsigned int)u.s) << 16;
    return w.f;
}
__device__ inline bf16_t f2bf(float f) {
    union { unsigned int i; float f; } w; w.f = f;
    unsigned int r = (w.i + 0x7FFFu + ((w.i >> 16) & 1u)) >> 16;
    union { unsigned short s; __bf16 b; } u; u.s = (unsigned short)r;
    return u.b;
}

enum EpiMode { EPI_NONE = 0, EPI_BIAS_ROW = 1, EPI_BIAS_COL = 2, EPI_SCALE = 3 };

// ---- dtype probe: mode=1 if x is fp32, mode=0 if bf16 ----
__global__ void detect_mode(const unsigned short* __restrict__ x, int* __restrict__ mode)
{
    if (threadIdx.x == 0 && blockIdx.x == 0) {
        int hits = 0;
        for (int i = 0; i < 2048; ++i) {
            unsigned e = (x[i] >> 7) & 0xFFu;
            hits += (e >= 0x8Du) ? 1 : 0;
        }
        *mode = (hits >= 16) ? 1 : 0;
    }
}

// ---- convert x (elements [off, off+n8*8)) to bf16 ----
__global__ void convert_x(const void* __restrict__ xin, bf16_t* __restrict__ xb,
                          const int* __restrict__ modep, long long off, long long n8)
{
    const long long i = (long long)blockIdx.x * blockDim.x + threadIdx.x;
    if (i >= n8) return;
    bf16x8 o;
    if (*modep) {
        const float* s = (const float*)xin + off + i * 8;
#pragma unroll
        for (int j = 0; j < 8; ++j) o[j] = f2bf(s[j]);
    } else {
        o = *(const bf16x8*)((const bf16_t*)xin + off + i * 8);
    }
    *(bf16x8*)(xb + i * 8) = o;
}

// ---- transpose the three weight matrices -> bf16 Wt[n][k] = W[k][n] ----
__global__ void transpose3(const void* __restrict__ Wq, const void* __restrict__ Wk,
                           const void* __restrict__ Wv, bf16_t* __restrict__ Wt,
                           const int* __restrict__ modep)
{
    const int md = *modep;
    const void* src = (blockIdx.z == 0) ? Wq : (blockIdx.z == 1) ? Wk : Wv;
    bf16_t* dst = Wt + (size_t)blockIdx.z * DM * DM;
    __shared__ bf16_t T[64][72];
    const int tid = threadIdx.x;
    const int r  = tid >> 2;   // 0..63
    const int cp = tid & 3;    // 16 elems each
    const int r0 = blockIdx.y * 64;  // k block
    const int c0 = blockIdx.x * 64;  // n block
    const size_t base = (size_t)(r0 + r) * DM + c0 + cp * 16;
    bf16_t tmp[16];
    if (md) {
        const float* s = (const float*)src + base;
#pragma unroll
        for (int j = 0; j < 16; ++j) tmp[j] = f2bf(s[j]);
    } else {
        const bf16_t* s = (const bf16_t*)src + base;
        bf16x8 a = *(const bf16x8*)s;
        bf16x8 b = *(const bf16x8*)(s + 8);
#pragma unroll
        for (int j = 0; j < 8; ++j) { tmp[j] = a[j]; tmp[8 + j] = b[j]; }
    }
#pragma unroll
    for (int j = 0; j < 16; ++j) T[cp * 16 + j][r] = tmp[j];
    __syncthreads();
    bf16_t* d = dst + (size_t)(c0 + r) * DM + r0 + cp * 16;
    bf16x8 w0, w1;
#pragma unroll
    for (int j = 0; j < 8; ++j) w0[j] = T[r][cp * 16 + j];
#pragma unroll
    for (int j = 0; j < 8; ++j) w1[j] = T[r][cp * 16 + 8 + j];
    *(bf16x8*)d = w0;
    *(bf16x8*)(d + 8) = w1;
}

// NT gemm: C[M,N] = A[M,K] * B[N,K]^T, bf16 in, fp32 accum.
// Tile 128x128, BK=64, 256 threads (4 waves 2x2, 4x4 mfma 16x16x32 each).
// R0 change vs previous session: (a) staging via global_load_lds width=16
// (m97 structure, measured +35% vs reg-staging at this tile), (b) bijective
// XCD-aware block swizzle so each XCD owns whole z-slices (4MB panel set
// fits the per-XCD 4MB L2).
template <int MODE, bool DUALOUT>
__global__ __launch_bounds__(256, 2)
void gemm_nt(const bf16_t* __restrict__ A, long long sA,
             const bf16_t* __restrict__ B, long long sB,
             void* __restrict__ C, long long sC, long long cOff,
             const void* __restrict__ bias, const int* __restrict__ modep,
             int M, int N, int K, float scale)
{
    constexpr int BM = 128, BN = 128, BK = 64;
    __shared__ __align__(16) bf16_t As[BM * BK];
    __shared__ __align__(16) bf16_t Bs[BN * BK];

    // ---- XCD-aware bijective swizzle (T1, m204 form; nwg = 64*zb % 8 == 0) ----
    const int Gx = gridDim.x, Gy = gridDim.y;
    const int nwg = Gx * Gy * (int)gridDim.z;
    int bx = blockIdx.x, by = blockIdx.y, z = blockIdx.z;
    if ((nwg & 7) == 0) {
        const int orig = bx + Gx * (by + Gy * z);
        const int nper = nwg >> 3;
        const int nid  = (orig & 7) * nper + (orig >> 3);
        bx = nid % Gx;
        by = (nid / Gx) % Gy;
        z  = nid / (Gx * Gy);
    }

    const bf16_t* Ab = A + (size_t)z * (size_t)sA;
    const bf16_t* Bb = B + (size_t)z * (size_t)sB;

    const int gm0 = by * BM;
    const int gn0 = bx * BN;

    const int tid  = threadIdx.x;
    const int wave = tid >> 6;
    const int lane = tid & 63;
    const int wm   = (wave >> 1) * 64;
    const int wn   = (wave & 1) * 64;
    const int lm   = lane & 15;
    const int quad = lane >> 4;

    f32x4 acc[4][4];
#pragma unroll
    for (int i = 0; i < 4; ++i)
#pragma unroll
        for (int j = 0; j < 4; ++j) acc[i][j] = (f32x4)0.0f;

    const int nIter = K / BK;

    // chunk ch = tid + i*256; row = ch>>3 (0..127), kc = ch&7 (16B chunks)
    // LDS byte offset = ch*16 -> wave-uniform base + lane*16 (gload_lds-legal)
    auto stage = [&](int it) {
#pragma unroll
        for (int i = 0; i < 4; ++i) {
            const int ch = tid + i * 256;
            const int row = ch >> 3, kc = ch & 7;
            async_lds16(Ab + (size_t)(gm0 + row) * K + it * BK + kc * 8,
                        As + ch * 8);
            async_lds16(Bb + (size_t)(gn0 + row) * K + it * BK + kc * 8,
                        Bs + ch * 8);
        }
    };

    for (int it = 0; it < nIter; ++it) {
        if (it != 0) __syncthreads();   // prior iter's LDS reads done before overwrite
        stage(it);                      // async global->LDS, 16B/lane
        __syncthreads();                // drains vmcnt -> tile visible to all waves
#pragma unroll
        for (int kh = 0; kh < 2; ++kh) {
            bf16x8 af[4], bg[4];
#pragma unroll
            for (int mt = 0; mt < 4; ++mt) {
                const int m = wm + mt * 16 + lm;
                af[mt] = *(const bf16x8*)&As[m * BK + (kh * 4 + quad) * 8];
            }
#pragma unroll
            for (int nt = 0; nt < 4; ++nt) {
                const int n = wn + nt * 16 + lm;
                bg[nt] = *(const bf16x8*)&Bs[n * BK + (kh * 4 + quad) * 8];
            }
#pragma unroll
            for (int mt = 0; mt < 4; ++mt)
#pragma unroll
                for (int nt = 0; nt < 4; ++nt)
                    acc[mt][nt] = __builtin_amdgcn_mfma_f32_16x16x32_bf16(
                        af[mt], bg[nt], acc[mt][nt], 0, 0, 0);
        }
    }

    // epilogue: C/D layout col=lane&15, row=quad*4+r (m89/m91-verified)
    const int md = *modep;
#pragma unroll
    for (int mt = 0; mt < 4; ++mt) {
        float rbias[4];
        if (MODE == EPI_BIAS_ROW) {
#pragma unroll
            for (int r = 0; r < 4; ++r) {
                const int i = gm0 + wm + mt * 16 + quad * 4 + r;
                rbias[r] = md ? ((const float*)bias)[i] : bf2f(((const bf16_t*)bias)[i]);
            }
        }
#pragma unroll
        for (int nt = 0; nt < 4; ++nt) {
            const int col = gn0 + wn + nt * 16 + lm;
            float cbias = 0.f;
            if (MODE == EPI_BIAS_COL)
                cbias = md ? ((const float*)bias)[col] : bf2f(((const bf16_t*)bias)[col]);
#pragma unroll
            for (int r = 0; r < 4; ++r) {
                const int row = gm0 + wm + mt * 16 + quad * 4 + r;
                float v = acc[mt][nt][r];
                if (MODE == EPI_BIAS_ROW) v += rbias[r];
                if (MODE == EPI_BIAS_COL) v += cbias;
                if (MODE == EPI_SCALE)    v *= scale;
                const size_t off = (size_t)cOff + (size_t)z * sC + (size_t)row * N + col;
                if (DUALOUT && md) ((float*)C)[off] = v;
                else               ((bf16_t*)C)[off] = f2bf(v);
            }
        }
    }
}

// In-place chunked softmax + transpose on Y[zb][DM][DM] (bf16 internal):
// Y <- Yt with Yt[b][e][d] = softmax_64chunk(Y[b][d][:])[e]. Softmax axis is
// tile-aligned, so tile (I,J) softmaxes locally and swaps with (J,I);
// disjoint pairs across blocks -> race-free.
__global__ void softmax_t_inplace(bf16_t* __restrict__ Y)
{
    const int b = blockIdx.z;
    int idx = blockIdx.x;           // 0..135
    int I = 0;
    while (idx >= 16 - I) { idx -= 16 - I; ++I; }
    const int J = I + idx;

    const int tid = threadIdx.x;
    const int r  = tid >> 2;
    const int cp = tid & 3;

    bf16_t* base = Y + ((size_t)b << 20);
    bf16_t* t0 = base + (size_t)(I * 64 + r) * DM + J * 64 + cp * 16;
    bf16_t* t1 = base + (size_t)(J * 64 + r) * DM + I * 64 + cp * 16;

    __shared__ bf16_t P0[64][72];
    __shared__ bf16_t P1[64][72];

    bf16x8 a0 = *(const bf16x8*)t0;
    bf16x8 a1 = *(const bf16x8*)(t0 + 8);
    bf16x8 c0v, c1v;
    if (J != I) { c0v = *(const bf16x8*)t1; c1v = *(const bf16x8*)(t1 + 8); }

    {
        float f[16];
#pragma unroll
        for (int j = 0; j < 8; ++j) f[j] = bf2f(a0[j]);
#pragma unroll
        for (int j = 0; j < 8; ++j) f[8 + j] = bf2f(a1[j]);
        float m = -1e30f;
#pragma unroll
        for (int j = 0; j < 16; ++j) m = fmaxf(m, f[j]);
        m = fmaxf(m, __shfl_xor(m, 1));
        m = fmaxf(m, __shfl_xor(m, 2));
        float s = 0.f;
#pragma unroll
        for (int j = 0; j < 16; ++j) { f[j] = __expf(f[j] - m); s += f[j]; }
        s += __shfl_xor(s, 1);
        s += __shfl_xor(s, 2);
        const float inv = 1.0f / s;
#pragma unroll
        for (int j = 0; j < 16; ++j) P0[cp * 16 + j][r] = f2bf(f[j] * inv);
    }
    if (J != I) {
        float f[16];
#pragma unroll
        for (int j = 0; j < 8; ++j) f[j] = bf2f(c0v[j]);
#pragma unroll
        for (int j = 0; j < 8; ++j) f[8 + j] = bf2f(c1v[j]);
        float m = -1e30f;
#pragma unroll
        for (int j = 0; j < 16; ++j) m = fmaxf(m, f[j]);
        m = fmaxf(m, __shfl_xor(m, 1));
        m = fmaxf(m, __shfl_xor(m, 2));
        float s = 0.f;
#pragma unroll
        for (int j = 0; j < 16; ++j) { f[j] = __expf(f[j] - m); s += f[j]; }
        s += __shfl_xor(s, 1);
        s += __shfl_xor(s, 2);
        const float inv = 1.0f / s;
#pragma unroll
        for (int j = 0; j < 16; ++j) P1[cp * 16 + j][r] = f2bf(f[j] * inv);
    }
    __syncthreads();

    bf16x8 w0, w1;
#pragma unroll
    for (int j = 0; j < 8; ++j) w0[j] = P0[r][cp * 16 + j];
#pragma unroll
    for (int j = 0; j < 8; ++j) w1[j] = P0[r][cp * 16 + 8 + j];
    *(bf16x8*)t1 = w0;
    *(bf16x8*)(t1 + 8) = w1;
    if (J != I) {
#pragma unroll
        for (int j = 0; j < 8; ++j) w0[j] = P1[r][cp * 16 + j];
#pragma unroll
        for (int j = 0; j < 8; ++j) w1[j] = P1[r][cp * 16 + 8 + j];
        *(bf16x8*)t0 = w0;
        *(bf16x8*)(t0 + 8) = w1;
    }
}

extern "C" void kernel_launch(void* const* d_in, const int* in_sizes, int n_in,
                              void* d_out, int out_size, void* d_ws, size_t ws_size,
                              hipStream_t stream)
{
    const void* x  = d_in[0];
    const void* Wq = d_in[1];
    const void* bq = d_in[2];
    const void* Wk = d_in[3];
    const void* bk = d_in[4];
    const void* Wv = d_in[5];
    const void* bv = d_in[6];

    // ws layout: [mode int | pad to 256] [Wt 6MB] [xb CB] [qt CB] [kt CB] [y CB]
    char* ws = (char*)d_ws;
    int* mode = (int*)ws;
    const size_t MB2 = (size_t)DM * DM * 2;
    const size_t hdr = 256;
    int CB = NB;
    while (CB > 1 && hdr + 3 * MB2 + 4 * (size_t)CB * MB2 > ws_size) CB >>= 1;

    bf16_t* Wt = (bf16_t*)(ws + hdr);
    bf16_t* xb = (bf16_t*)(ws + hdr + 3 * MB2);
    bf16_t* qt = xb + (size_t)CB * DM * DM;
    bf16_t* kt = qt + (size_t)CB * DM * DM;
    bf16_t* y  = kt + (size_t)CB * DM * DM;
    bf16_t* v  = qt;   // qt dead after QK^T; reuse for V

    detect_mode<<<1, 64, 0, stream>>>((const unsigned short*)x, mode);
    transpose3<<<dim3(16, 16, 3), 256, 0, stream>>>(Wq, Wk, Wv, Wt, mode);

    const long long msz = (long long)DM * DM;
    for (int c = 0; c < NB; c += CB) {
        const int zb = (NB - c < CB) ? (NB - c) : CB;
        const long long n8 = (long long)zb * msz / 8;
        convert_x<<<(int)((n8 + 255) / 256), 256, 0, stream>>>(x, xb, mode, (long long)c * msz, n8);

        const dim3 g(8, 8, zb), blk(256);
        // qt[b][d][s] = Wq^T x^T + bq (row bias)
        gemm_nt<EPI_BIAS_ROW, false><<<g, blk, 0, stream>>>(Wt, 0, xb, msz, qt, msz, 0, bq, mode, DM, DM, DM, 1.f);
        // kt[b][e][s]
        gemm_nt<EPI_BIAS_ROW, false><<<g, blk, 0, stream>>>(Wt + msz, 0, xb, msz, kt, msz, 0, bk, mode, DM, DM, DM, 1.f);
        // y[b][d][e] = qt . kt / 8
        gemm_nt<EPI_SCALE, false><<<g, blk, 0, stream>>>(qt, msz, kt, msz, y, msz, 0, nullptr, mode, DM, DM, DM, 0.125f);
        // y <- softmax+transpose in place
        softmax_t_inplace<<<dim3(136, 1, zb), 256, 0, stream>>>(y);
        // v[b][s][d] = x Wv^T + bv (col bias) -> qt slab
        gemm_nt<EPI_BIAS_COL, false><<<g, blk, 0, stream>>>(xb, msz, Wt + 2 * msz, 0, v, msz, 0, bv, mode, DM, DM, DM, 1.f);
        // out[b][s][e] = v . y   (dual-dtype output)
        gemm_nt<EPI_NONE, true><<<g, blk, 0, stream>>>(v, msz, y, msz, d_out, msz, (long long)c * msz, nullptr, mode, DM, DM, DM, 1.f);
    }
}

// Round 2
// 698.688 us; speedup vs baseline: 1.1447x; 1.0917x over previous
//
#include <hip/hip_runtime.h>
#include <hip/hip_bf16.h>

// Problem: B=32, S=1024, D=1024, dm=1024, 16 heads x 64
#define DM 1024
#define NB 32

typedef __bf16 bf16_t;
typedef __attribute__((ext_vector_type(8))) __bf16 bf16x8;
typedef __attribute__((ext_vector_type(4))) float  f32x4;

// address-space typedefs for global_load_lds
typedef __attribute__((address_space(1))) void gas_void;
typedef __attribute__((address_space(3))) void las_void;

__device__ __forceinline__ void async_lds16(const bf16_t* g, bf16_t* l) {
    // 16B/lane direct global->LDS DMA. LDS dest must be wave-uniform base +
    // lane*16 (all call sites obey: lds byte = (i*512 + tid)*16).
    __builtin_amdgcn_global_load_lds((gas_void*)g, (las_void*)l, 16, 0, 0);
}

__device__ inline float bf2f(bf16_t v) {
    union { unsigned short s; __bf16 b; } u; u.b = v;
    union { unsigned int i; float f; } w; w.i = ((unsigned int)u.s) << 16;
    return w.f;
}
__device__ inline bf16_t f2bf(float f) {
    union { unsigned int i; float f; } w; w.f = f;
    unsigned int r = (w.i + 0x7FFFu + ((w.i >> 16) & 1u)) >> 16;
    union { unsigned short s; __bf16 b; } u; u.s = (unsigned short)r;
    return u.b;
}

enum EpiMode { EPI_NONE = 0, EPI_BIAS_ROW = 1, EPI_BIAS_COL = 2, EPI_SCALE = 3 };

// ---- dtype probe: mode=1 if x is fp32, mode=0 if bf16 ----
__global__ void detect_mode(const unsigned short* __restrict__ x, int* __restrict__ mode)
{
    if (threadIdx.x == 0 && blockIdx.x == 0) {
        int hits = 0;
        for (int i = 0; i < 2048; ++i) {
            unsigned e = (x[i] >> 7) & 0xFFu;
            hits += (e >= 0x8Du) ? 1 : 0;
        }
        *mode = (hits >= 16) ? 1 : 0;
    }
}

// ---- convert x (elements [off, off+n8*8)) to bf16 ----
__global__ void convert_x(const void* __restrict__ xin, bf16_t* __restrict__ xb,
                          const int* __restrict__ modep, long long off, long long n8)
{
    const long long i = (long long)blockIdx.x * blockDim.x + threadIdx.x;
    if (i >= n8) return;
    bf16x8 o;
    if (*modep) {
        const float* s = (const float*)xin + off + i * 8;
#pragma unroll
        for (int j = 0; j < 8; ++j) o[j] = f2bf(s[j]);
    } else {
        o = *(const bf16x8*)((const bf16_t*)xin + off + i * 8);
    }
    *(bf16x8*)(xb + i * 8) = o;
}

// ---- transpose the three weight matrices -> bf16 Wt[n][k] = W[k][n] ----
__global__ void transpose3(const void* __restrict__ Wq, const void* __restrict__ Wk,
                           const void* __restrict__ Wv, bf16_t* __restrict__ Wt,
                           const int* __restrict__ modep)
{
    const int md = *modep;
    const void* src = (blockIdx.z == 0) ? Wq : (blockIdx.z == 1) ? Wk : Wv;
    bf16_t* dst = Wt + (size_t)blockIdx.z * DM * DM;
    __shared__ bf16_t T[64][72];
    const int tid = threadIdx.x;
    const int r  = tid >> 2;   // 0..63
    const int cp = tid & 3;    // 16 elems each
    const int r0 = blockIdx.y * 64;  // k block
    const int c0 = blockIdx.x * 64;  // n block
    const size_t base = (size_t)(r0 + r) * DM + c0 + cp * 16;
    bf16_t tmp[16];
    if (md) {
        const float* s = (const float*)src + base;
#pragma unroll
        for (int j = 0; j < 16; ++j) tmp[j] = f2bf(s[j]);
    } else {
        const bf16_t* s = (const bf16_t*)src + base;
        bf16x8 a = *(const bf16x8*)s;
        bf16x8 b = *(const bf16x8*)(s + 8);
#pragma unroll
        for (int j = 0; j < 8; ++j) { tmp[j] = a[j]; tmp[8 + j] = b[j]; }
    }
#pragma unroll
    for (int j = 0; j < 16; ++j) T[cp * 16 + j][r] = tmp[j];
    __syncthreads();
    bf16_t* d = dst + (size_t)(c0 + r) * DM + r0 + cp * 16;
    bf16x8 w0, w1;
#pragma unroll
    for (int j = 0; j < 8; ++j) w0[j] = T[r][cp * 16 + j];
#pragma unroll
    for (int j = 0; j < 8; ++j) w1[j] = T[r][cp * 16 + 8 + j];
    *(bf16x8*)d = w0;
    *(bf16x8*)(d + 8) = w1;
}

// ============================================================================
// 8-phase 256x256 NT gemm (T2+T3+T4+T5): C[1024,1024] = A[1024,1024]*B^T.
// 512 threads = 8 waves; per K-tile (BK=64) 4 phases, phase p computes output
// quadrant (p>>1, p&1) over full K=64 (16 MFMA 16x16x32) and stages slot p of
// the NEXT K-tile into the other LDS buffer. Slots: 0=A-half0, 1=B-half0,
// 2=B-half1, 3=A-half1 (first-use order). LDS = 2 bufs x 4 slots x 16KiB.
// Counted vmcnt (never 0 in-loop): vmcnt(4) @phase1-end guarantees this
// tile's slot3; vmcnt(2) @phase3-end guarantees next tile's slots 0..2.
// Swizzle (T2): LDS dest linear (gload_lds constraint), global SOURCE chunk
// index kc ^= (row&7); fragment reads apply the same XOR -> 2-way max.
// ============================================================================
template <int MODE, bool DUALOUT>
__global__ __launch_bounds__(512, 2)
void gemm_nt8(const bf16_t* __restrict__ A, long long sA,
              const bf16_t* __restrict__ B, long long sB,
              void* __restrict__ C, long long sC, long long cOff,
              const void* __restrict__ bias, const int* __restrict__ modep,
              float scale)
{
    constexpr int K = 1024;
    constexpr int NT = K / 64;          // 16 K-tiles
    extern __shared__ bf16_t L[];       // 2*4*8192 bf16 = 128 KiB

    // ---- XCD-aware bijective swizzle (grid is 4 x 4 x z, nwg % 8 == 0) ----
    int bx, by, z;
    {
        const int nwg  = 16 * (int)gridDim.z;
        const int orig = (int)blockIdx.x + 4 * ((int)blockIdx.y + 4 * (int)blockIdx.z);
        const int nid  = (orig & 7) * (nwg >> 3) + (orig >> 3);
        bx = nid & 3; by = (nid >> 2) & 3; z = nid >> 4;
    }

    const bf16_t* Ab = A + (size_t)z * (size_t)sA;
    const bf16_t* Bb = B + (size_t)z * (size_t)sB;
    const int gm0 = by * 256, gn0 = bx * 256;

    const int tid  = threadIdx.x;
    const int lane = tid & 63;
    const int w    = tid >> 6;      // 0..7
    const int rb   = w >> 1;        // 0..3: 32-row block within quadrant
    const int cb   = w & 1;         // 0..1: 64-col block within quadrant
    const int lm   = lane & 15;
    const int kg   = lane >> 4;     // 0..3

    f32x4 acc[4][2][4];
#pragma unroll
    for (int p = 0; p < 4; ++p)
#pragma unroll
        for (int i = 0; i < 2; ++i)
#pragma unroll
            for (int j = 0; j < 4; ++j) acc[p][i][j] = (f32x4)0.0f;

    // stage slot s of K-tile kt into buffer b (2 x global_load_lds / thread)
    auto stage = [&](int kt, int s, int b) {
        const bf16_t* P  = (s == 0 || s == 3) ? Ab : Bb;
        const int     g0 = (s == 0 || s == 3) ? gm0 : gn0;
        const int     h  = (s >= 2) ? 1 : 0;     // s2(B),s3(A) are half 1
        bf16_t* dst = L + (b * 4 + s) * 8192;
#pragma unroll
        for (int i = 0; i < 2; ++i) {
            const int ci  = i * 512 + tid;
            const int row = ci >> 3;
            const int kc  = (ci & 7) ^ (row & 7);   // pre-swizzled source
            async_lds16(P + (size_t)(g0 + h * 128 + row) * K + kt * 64 + kc * 8,
                        dst + ci * 8);
        }
    };

    // fragment read: row r (0..127) of a half-slot, 8-elem chunk kc (0..7)
    auto rdfrag = [&](int b, int s, int r, int kc) -> bf16x8 {
        const int byte = r * 128 + ((kc ^ (r & 7)) * 16);
        return *(const bf16x8*)((const char*)(L + (b * 4 + s) * 8192) + byte);
    };

    // ---- prologue: tile 0's 4 slots; wait so slots 0..2 are resident ----
#pragma unroll
    for (int s = 0; s < 4; ++s) stage(0, s, 0);
    asm volatile("s_waitcnt vmcnt(2)" ::: "memory");
    __builtin_amdgcn_s_barrier();

#pragma unroll 1
    for (int kt = 0; kt < NT; ++kt) {
        const int cur = kt & 1;
        const int nkt = (kt + 1 < NT) ? kt + 1 : 0;   // dummy re-stage on last
#pragma unroll
        for (int p = 0; p < 4; ++p) {
            const int sA_ = (p >> 1) ? 3 : 0;
            const int sB_ = (p & 1) ? 2 : 1;
            // ds-load this phase's fragments (12 x ds_read_b128)
            bf16x8 af[2][2], bg[4][2];
#pragma unroll
            for (int mt = 0; mt < 2; ++mt)
#pragma unroll
                for (int kk = 0; kk < 2; ++kk)
                    af[mt][kk] = rdfrag(cur, sA_, rb * 32 + mt * 16 + lm, kk * 4 + kg);
#pragma unroll
            for (int nt = 0; nt < 4; ++nt)
#pragma unroll
                for (int kk = 0; kk < 2; ++kk)
                    bg[nt][kk] = rdfrag(cur, sB_, cb * 64 + nt * 16 + lm, kk * 4 + kg);
            // stage slot p of next tile into the other buffer
            stage(nkt, p, cur ^ 1);
            __builtin_amdgcn_s_barrier();
            asm volatile("s_waitcnt lgkmcnt(0)" ::: "memory");
            __builtin_amdgcn_sched_barrier(0);
            __builtin_amdgcn_s_setprio(1);
#pragma unroll
            for (int kk = 0; kk < 2; ++kk)
#pragma unroll
                for (int mt = 0; mt < 2; ++mt)
#pragma unroll
                    for (int nt = 0; nt < 4; ++nt)
                        acc[p][mt][nt] = __builtin_amdgcn_mfma_f32_16x16x32_bf16(
                            af[mt][kk], bg[nt][kk], acc[p][mt][nt], 0, 0, 0);
            __builtin_amdgcn_s_setprio(0);
            if (p == 1) { asm volatile("s_waitcnt vmcnt(4)" ::: "memory"); }
            if (p == 3) { asm volatile("s_waitcnt vmcnt(2)" ::: "memory"); }
            __builtin_amdgcn_s_barrier();
        }
    }

    // ---- epilogue: C/D layout col=lane&15, row=kg*4+r (m89/m91-verified) ----
    const int md = *modep;
#pragma unroll
    for (int p = 0; p < 4; ++p) {
        const int rbase = gm0 + (p >> 1) * 128 + rb * 32;
        const int cbase = gn0 + (p & 1) * 128 + cb * 64;
#pragma unroll
        for (int mt = 0; mt < 2; ++mt) {
            float rbias[4];
            if (MODE == EPI_BIAS_ROW) {
#pragma unroll
                for (int r = 0; r < 4; ++r) {
                    const int i = rbase + mt * 16 + kg * 4 + r;
                    rbias[r] = md ? ((const float*)bias)[i] : bf2f(((const bf16_t*)bias)[i]);
                }
            }
#pragma unroll
            for (int nt = 0; nt < 4; ++nt) {
                const int col = cbase + nt * 16 + lm;
                float cbias = 0.f;
                if (MODE == EPI_BIAS_COL)
                    cbias = md ? ((const float*)bias)[col] : bf2f(((const bf16_t*)bias)[col]);
#pragma unroll
                for (int r = 0; r < 4; ++r) {
                    const int row = rbase + mt * 16 + kg * 4 + r;
                    float vv = acc[p][mt][nt][r];
                    if (MODE == EPI_BIAS_ROW) vv += rbias[r];
                    if (MODE == EPI_BIAS_COL) vv += cbias;
                    if (MODE == EPI_SCALE)    vv *= scale;
                    const size_t off = (size_t)cOff + (size_t)z * sC + (size_t)row * 1024 + col;
                    if (DUALOUT && md) ((float*)C)[off] = vv;
                    else               ((bf16_t*)C)[off] = f2bf(vv);
                }
            }
        }
    }
}

// In-place chunked softmax + transpose on Y[zb][DM][DM] (bf16 internal).
__global__ void softmax_t_inplace(bf16_t* __restrict__ Y)
{
    const int b = blockIdx.z;
    int idx = blockIdx.x;           // 0..135
    int I = 0;
    while (idx >= 16 - I) { idx -= 16 - I; ++I; }
    const int J = I + idx;

    const int tid = threadIdx.x;
    const int r  = tid >> 2;
    const int cp = tid & 3;

    bf16_t* base = Y + ((size_t)b << 20);
    bf16_t* t0 = base + (size_t)(I * 64 + r) * DM + J * 64 + cp * 16;
    bf16_t* t1 = base + (size_t)(J * 64 + r) * DM + I * 64 + cp * 16;

    __shared__ bf16_t P0[64][72];
    __shared__ bf16_t P1[64][72];

    bf16x8 a0 = *(const bf16x8*)t0;
    bf16x8 a1 = *(const bf16x8*)(t0 + 8);
    bf16x8 c0v, c1v;
    if (J != I) { c0v = *(const bf16x8*)t1; c1v = *(const bf16x8*)(t1 + 8); }

    {
        float f[16];
#pragma unroll
        for (int j = 0; j < 8; ++j) f[j] = bf2f(a0[j]);
#pragma unroll
        for (int j = 0; j < 8; ++j) f[8 + j] = bf2f(a1[j]);
        float m = -1e30f;
#pragma unroll
        for (int j = 0; j < 16; ++j) m = fmaxf(m, f[j]);
        m = fmaxf(m, __shfl_xor(m, 1));
        m = fmaxf(m, __shfl_xor(m, 2));
        float s = 0.f;
#pragma unroll
        for (int j = 0; j < 16; ++j) { f[j] = __expf(f[j] - m); s += f[j]; }
        s += __shfl_xor(s, 1);
        s += __shfl_xor(s, 2);
        const float inv = 1.0f / s;
#pragma unroll
        for (int j = 0; j < 16; ++j) P0[cp * 16 + j][r] = f2bf(f[j] * inv);
    }
    if (J != I) {
        float f[16];
#pragma unroll
        for (int j = 0; j < 8; ++j) f[j] = bf2f(c0v[j]);
#pragma unroll
        for (int j = 0; j < 8; ++j) f[8 + j] = bf2f(c1v[j]);
        float m = -1e30f;
#pragma unroll
        for (int j = 0; j < 16; ++j) m = fmaxf(m, f[j]);
        m = fmaxf(m, __shfl_xor(m, 1));
        m = fmaxf(m, __shfl_xor(m, 2));
        float s = 0.f;
#pragma unroll
        for (int j = 0; j < 16; ++j) { f[j] = __expf(f[j] - m); s += f[j]; }
        s += __shfl_xor(s, 1);
        s += __shfl_xor(s, 2);
        const float inv = 1.0f / s;
#pragma unroll
        for (int j = 0; j < 16; ++j) P1[cp * 16 + j][r] = f2bf(f[j] * inv);
    }
    __syncthreads();

    bf16x8 w0, w1;
#pragma unroll
    for (int j = 0; j < 8; ++j) w0[j] = P0[r][cp * 16 + j];
#pragma unroll
    for (int j = 0; j < 8; ++j) w1[j] = P0[r][cp * 16 + 8 + j];
    *(bf16x8*)t1 = w0;
    *(bf16x8*)(t1 + 8) = w1;
    if (J != I) {
#pragma unroll
        for (int j = 0; j < 8; ++j) w0[j] = P1[r][cp * 16 + j];
#pragma unroll
        for (int j = 0; j < 8; ++j) w1[j] = P1[r][cp * 16 + 8 + j];
        *(bf16x8*)t0 = w0;
        *(bf16x8*)(t0 + 8) = w1;
    }
}

extern "C" void kernel_launch(void* const* d_in, const int* in_sizes, int n_in,
                              void* d_out, int out_size, void* d_ws, size_t ws_size,
                              hipStream_t stream)
{
    const void* x  = d_in[0];
    const void* Wq = d_in[1];
    const void* bq = d_in[2];
    const void* Wk = d_in[3];
    const void* bk = d_in[4];
    const void* Wv = d_in[5];
    const void* bv = d_in[6];

    // one-time: allow 128 KiB dynamic LDS on the gemm instantiations
    static bool attr_done = false;
    if (!attr_done) {
        hipFuncSetAttribute((const void*)gemm_nt8<EPI_BIAS_ROW, false>,
                            hipFuncAttributeMaxDynamicSharedMemorySize, 131072);
        hipFuncSetAttribute((const void*)gemm_nt8<EPI_BIAS_COL, false>,
                            hipFuncAttributeMaxDynamicSharedMemorySize, 131072);
        hipFuncSetAttribute((const void*)gemm_nt8<EPI_SCALE, false>,
                            hipFuncAttributeMaxDynamicSharedMemorySize, 131072);
        hipFuncSetAttribute((const void*)gemm_nt8<EPI_NONE, true>,
                            hipFuncAttributeMaxDynamicSharedMemorySize, 131072);
        attr_done = true;
    }

    // ws layout: [mode int | pad to 256] [Wt 6MB] [xb CB] [qt CB] [kt CB] [y CB]
    char* ws = (char*)d_ws;
    int* mode = (int*)ws;
    const size_t MB2 = (size_t)DM * DM * 2;
    const size_t hdr = 256;
    int CB = NB;
    while (CB > 1 && hdr + 3 * MB2 + 4 * (size_t)CB * MB2 > ws_size) CB >>= 1;

    bf16_t* Wt = (bf16_t*)(ws + hdr);
    bf16_t* xb = (bf16_t*)(ws + hdr + 3 * MB2);
    bf16_t* qt = xb + (size_t)CB * DM * DM;
    bf16_t* kt = qt + (size_t)CB * DM * DM;
    bf16_t* y  = kt + (size_t)CB * DM * DM;
    bf16_t* v  = qt;   // qt dead after QK^T; reuse for V

    detect_mode<<<1, 64, 0, stream>>>((const unsigned short*)x, mode);
    transpose3<<<dim3(16, 16, 3), 256, 0, stream>>>(Wq, Wk, Wv, Wt, mode);

    const long long msz = (long long)DM * DM;
    for (int c = 0; c < NB; c += CB) {
        const int zb = (NB - c < CB) ? (NB - c) : CB;
        const long long n8 = (long long)zb * msz / 8;
        convert_x<<<(int)((n8 + 255) / 256), 256, 0, stream>>>(x, xb, mode, (long long)c * msz, n8);

        const dim3 g8(4, 4, zb), blk8(512);
        // qt[b][d][s] = Wq^T x^T + bq (row bias)
        gemm_nt8<EPI_BIAS_ROW, false><<<g8, blk8, 131072, stream>>>(Wt, 0, xb, msz, qt, msz, 0, bq, mode, 1.f);
        // kt[b][e][s]
        gemm_nt8<EPI_BIAS_ROW, false><<<g8, blk8, 131072, stream>>>(Wt + msz, 0, xb, msz, kt, msz, 0, bk, mode, 1.f);
        // y[b][d][e] = qt . kt / 8
        gemm_nt8<EPI_SCALE, false><<<g8, blk8, 131072, stream>>>(qt, msz, kt, msz, y, msz, 0, nullptr, mode, 0.125f);
        // y <- softmax+transpose in place
        softmax_t_inplace<<<dim3(136, 1, zb), 256, 0, stream>>>(y);
        // v[b][s][d] = x Wv^T + bv (col bias) -> qt slab
        gemm_nt8<EPI_BIAS_COL, false><<<g8, blk8, 131072, stream>>>(xb, msz, Wt + 2 * msz, 0, v, msz, 0, bv, mode, 1.f);
        // out[b][s][e] = v . y   (dual-dtype output)
        gemm_nt8<EPI_NONE, true><<<g8, blk8, 131072, stream>>>(v, msz, y, msz, d_out, msz, (long long)c * msz, nullptr, mode, 1.f);
    }
}

// Round 3
// 675.383 us; speedup vs baseline: 1.1842x; 1.0345x over previous
//
#include <hip/hip_runtime.h>
#include <hip/hip_bf16.h>

// Problem: B=32, S=1024, D=1024, dm=1024, 16 heads x 64
#define DM 1024
#define NB 32

typedef __bf16 bf16_t;
typedef __attribute__((ext_vector_type(8))) __bf16 bf16x8;
typedef __attribute__((ext_vector_type(4))) float  f32x4;

// address-space typedefs for global_load_lds
typedef __attribute__((address_space(1))) void gas_void;
typedef __attribute__((address_space(3))) void las_void;

__device__ __forceinline__ void async_lds16(const bf16_t* g, bf16_t* l) {
    // 16B/lane direct global->LDS DMA. LDS dest must be wave-uniform base +
    // lane*16 (all call sites obey: lds byte = (i*512 + tid)*16).
    __builtin_amdgcn_global_load_lds((gas_void*)g, (las_void*)l, 16, 0, 0);
}

__device__ inline float bf2f(bf16_t v) {
    union { unsigned short s; __bf16 b; } u; u.b = v;
    union { unsigned int i; float f; } w; w.i = ((unsigned int)u.s) << 16;
    return w.f;
}
__device__ inline bf16_t f2bf(float f) {
    union { unsigned int i; float f; } w; w.f = f;
    unsigned int r = (w.i + 0x7FFFu + ((w.i >> 16) & 1u)) >> 16;
    union { unsigned short s; __bf16 b; } u; u.s = (unsigned short)r;
    return u.b;
}

enum EpiMode { EPI_NONE = 0, EPI_BIAS_ROW = 1, EPI_BIAS_COL = 2, EPI_SCALE = 3 };

// ---- dtype probe: mode=1 if x is fp32, mode=0 if bf16 ----
__global__ void detect_mode(const unsigned short* __restrict__ x, int* __restrict__ mode)
{
    if (threadIdx.x == 0 && blockIdx.x == 0) {
        int hits = 0;
        for (int i = 0; i < 2048; ++i) {
            unsigned e = (x[i] >> 7) & 0xFFu;
            hits += (e >= 0x8Du) ? 1 : 0;
        }
        *mode = (hits >= 16) ? 1 : 0;
    }
}

// ---- convert x (elements [off, off+n8*8)) to bf16 ----
__global__ void convert_x(const void* __restrict__ xin, bf16_t* __restrict__ xb,
                          const int* __restrict__ modep, long long off, long long n8)
{
    const long long i = (long long)blockIdx.x * blockDim.x + threadIdx.x;
    if (i >= n8) return;
    bf16x8 o;
    if (*modep) {
        const float* s = (const float*)xin + off + i * 8;
#pragma unroll
        for (int j = 0; j < 8; ++j) o[j] = f2bf(s[j]);
    } else {
        o = *(const bf16x8*)((const bf16_t*)xin + off + i * 8);
    }
    *(bf16x8*)(xb + i * 8) = o;
}

// ---- transpose the three weight matrices -> bf16 Wt[n][k] = W[k][n] ----
__global__ void transpose3(const void* __restrict__ Wq, const void* __restrict__ Wk,
                           const void* __restrict__ Wv, bf16_t* __restrict__ Wt,
                           const int* __restrict__ modep)
{
    const int md = *modep;
    const void* src = (blockIdx.z == 0) ? Wq : (blockIdx.z == 1) ? Wk : Wv;
    bf16_t* dst = Wt + (size_t)blockIdx.z * DM * DM;
    __shared__ bf16_t T[64][72];
    const int tid = threadIdx.x;
    const int r  = tid >> 2;   // 0..63
    const int cp = tid & 3;    // 16 elems each
    const int r0 = blockIdx.y * 64;  // k block
    const int c0 = blockIdx.x * 64;  // n block
    const size_t base = (size_t)(r0 + r) * DM + c0 + cp * 16;
    bf16_t tmp[16];
    if (md) {
        const float* s = (const float*)src + base;
#pragma unroll
        for (int j = 0; j < 16; ++j) tmp[j] = f2bf(s[j]);
    } else {
        const bf16_t* s = (const bf16_t*)src + base;
        bf16x8 a = *(const bf16x8*)s;
        bf16x8 b = *(const bf16x8*)(s + 8);
#pragma unroll
        for (int j = 0; j < 8; ++j) { tmp[j] = a[j]; tmp[8 + j] = b[j]; }
    }
#pragma unroll
    for (int j = 0; j < 16; ++j) T[cp * 16 + j][r] = tmp[j];
    __syncthreads();
    bf16_t* d = dst + (size_t)(c0 + r) * DM + r0 + cp * 16;
    bf16x8 w0, w1;
#pragma unroll
    for (int j = 0; j < 8; ++j) w0[j] = T[r][cp * 16 + j];
#pragma unroll
    for (int j = 0; j < 8; ++j) w1[j] = T[r][cp * 16 + 8 + j];
    *(bf16x8*)d = w0;
    *(bf16x8*)(d + 8) = w1;
}

// ============================================================================
// 8-phase 256x256 NT gemm (T2+T3+T4+T5): C[1024,1024] = A[1024,1024]*B^T.
// 512 threads = 8 waves (wave rb=w>>1 owns 32-row band, cb=w&1 owns 64-col
// band, replicated across both 128-halves). Per K-tile (BK=64) 4 phases;
// phase p computes quadrant (row-half mh=p&1, col-half nh=p>>1), 16 MFMA.
// R3: fragment REGISTER-CACHING — each fragment ds_read ONCE per K-tile at
// first use (24 b128/wave/K-tile vs 48 in R2): p0 reads af0(4)+bg_h0(8),
// p1 reads af1(4), p2 reads bg_h1(8, reusing bg regs), p3 reads 0.
// Slots (first-use order): 0=A-h0, 1=B-h0, 2=A-h1, 3=B-h1.
// Counted vmcnt unchanged from R2 (never 0 in-loop): vmcnt(4)@p1-end
// guarantees slot3 (first read at p2); vmcnt(2)@p3-end guarantees next
// tile's slots 0..2 (reads at p0/p1).
// Swizzle (T2): LDS dest linear (gload_lds constraint), global SOURCE chunk
// kc ^= (row&7); fragment reads apply the same XOR -> conflict-free.
// ============================================================================
template <int MODE, bool DUALOUT>
__global__ __launch_bounds__(512, 2)
void gemm_nt8(const bf16_t* __restrict__ A, long long sA,
              const bf16_t* __restrict__ B, long long sB,
              void* __restrict__ C, long long sC, long long cOff,
              const void* __restrict__ bias, const int* __restrict__ modep,
              float scale)
{
    constexpr int K = 1024;
    constexpr int NT = K / 64;          // 16 K-tiles
    extern __shared__ bf16_t L[];       // 2*4*8192 bf16 = 128 KiB

    // ---- XCD-aware bijective swizzle (grid is 4 x 4 x z, nwg % 8 == 0) ----
    int bx, by, z;
    {
        const int nwg  = 16 * (int)gridDim.z;
        const int orig = (int)blockIdx.x + 4 * ((int)blockIdx.y + 4 * (int)blockIdx.z);
        const int nid  = (orig & 7) * (nwg >> 3) + (orig >> 3);
        bx = nid & 3; by = (nid >> 2) & 3; z = nid >> 4;
    }

    const bf16_t* Ab = A + (size_t)z * (size_t)sA;
    const bf16_t* Bb = B + (size_t)z * (size_t)sB;
    const int gm0 = by * 256, gn0 = bx * 256;

    const int tid  = threadIdx.x;
    const int lane = tid & 63;
    const int w    = tid >> 6;      // 0..7
    const int rb   = w >> 1;        // 0..3: 32-row band within each row-half
    const int cb   = w & 1;         // 0..1: 64-col band within each col-half
    const int lm   = lane & 15;
    const int kg   = lane >> 4;     // 0..3

    f32x4 acc[4][2][4];
#pragma unroll
    for (int p = 0; p < 4; ++p)
#pragma unroll
        for (int i = 0; i < 2; ++i)
#pragma unroll
            for (int j = 0; j < 4; ++j) acc[p][i][j] = (f32x4)0.0f;

    // stage slot s of K-tile kt into buffer b (2 x global_load_lds / thread)
    // slots: 0=A-h0, 1=B-h0, 2=A-h1, 3=B-h1
    auto stage = [&](int kt, int s, int b) {
        const bf16_t* P  = (s & 1) ? Bb : Ab;
        const int     g0 = (s & 1) ? gn0 : gm0;
        const int     h  = (s >= 2) ? 1 : 0;
        bf16_t* dst = L + (b * 4 + s) * 8192;
#pragma unroll
        for (int i = 0; i < 2; ++i) {
            const int ci  = i * 512 + tid;
            const int row = ci >> 3;
            const int kc  = (ci & 7) ^ (row & 7);   // pre-swizzled source
            async_lds16(P + (size_t)(g0 + h * 128 + row) * K + kt * 64 + kc * 8,
                        dst + ci * 8);
        }
    };

    // fragment read: row r (0..127) within a half-slot, 8-elem chunk kc (0..7)
    auto rdfrag = [&](int b, int s, int r, int kc) -> bf16x8 {
        const int byte = r * 128 + ((kc ^ (r & 7)) * 16);
        return *(const bf16x8*)((const char*)(L + (b * 4 + s) * 8192) + byte);
    };

    // ---- prologue: tile 0's 4 slots; vmcnt(2) -> slots 0..2 resident ----
#pragma unroll
    for (int s = 0; s < 4; ++s) stage(0, s, 0);
    asm volatile("s_waitcnt vmcnt(2)" ::: "memory");
    __builtin_amdgcn_s_barrier();

#pragma unroll 1
    for (int kt = 0; kt < NT; ++kt) {
        const int cur = kt & 1;
        const int nkt = (kt + 1 < NT) ? kt + 1 : 0;   // dummy re-stage on last
        bf16x8 af0[2][2], af1[2][2], bg[4][2];
#pragma unroll
        for (int p = 0; p < 4; ++p) {
            // register-cached fragment reads, at first use only
            if (p == 0) {
#pragma unroll
                for (int mt = 0; mt < 2; ++mt)
#pragma unroll
                    for (int kk = 0; kk < 2; ++kk)
                        af0[mt][kk] = rdfrag(cur, 0, rb * 32 + mt * 16 + lm, kk * 4 + kg);
#pragma unroll
                for (int nt = 0; nt < 4; ++nt)
#pragma unroll
                    for (int kk = 0; kk < 2; ++kk)
                        bg[nt][kk] = rdfrag(cur, 1, cb * 64 + nt * 16 + lm, kk * 4 + kg);
            } else if (p == 1) {
#pragma unroll
                for (int mt = 0; mt < 2; ++mt)
#pragma unroll
                    for (int kk = 0; kk < 2; ++kk)
                        af1[mt][kk] = rdfrag(cur, 2, rb * 32 + mt * 16 + lm, kk * 4 + kg);
            } else if (p == 2) {
#pragma unroll
                for (int nt = 0; nt < 4; ++nt)
#pragma unroll
                    for (int kk = 0; kk < 2; ++kk)
                        bg[nt][kk] = rdfrag(cur, 3, cb * 64 + nt * 16 + lm, kk * 4 + kg);
            }
            // stage slot p of next tile into the other buffer
            stage(nkt, p, cur ^ 1);
            __builtin_amdgcn_s_barrier();
            asm volatile("s_waitcnt lgkmcnt(0)" ::: "memory");
            __builtin_amdgcn_sched_barrier(0);
            __builtin_amdgcn_s_setprio(1);
#pragma unroll
            for (int kk = 0; kk < 2; ++kk)
#pragma unroll
                for (int mt = 0; mt < 2; ++mt)
#pragma unroll
                    for (int nt = 0; nt < 4; ++nt)
                        acc[p][mt][nt] = __builtin_amdgcn_mfma_f32_16x16x32_bf16(
                            (p & 1) ? af1[mt][kk] : af0[mt][kk],
                            bg[nt][kk], acc[p][mt][nt], 0, 0, 0);
            __builtin_amdgcn_s_setprio(0);
            if (p == 1) { asm volatile("s_waitcnt vmcnt(4)" ::: "memory"); }
            if (p == 3) { asm volatile("s_waitcnt vmcnt(2)" ::: "memory"); }
            __builtin_amdgcn_s_barrier();
        }
    }

    // ---- epilogue: C/D layout col=lane&15, row=kg*4+r (m89/m91-verified) ----
    // phase p = quadrant (row-half p&1, col-half p>>1)
    const int md = *modep;
#pragma unroll
    for (int p = 0; p < 4; ++p) {
        const int rbase = gm0 + (p & 1) * 128 + rb * 32;
        const int cbase = gn0 + (p >> 1) * 128 + cb * 64;
#pragma unroll
        for (int mt = 0; mt < 2; ++mt) {
            float rbias[4];
            if (MODE == EPI_BIAS_ROW) {
#pragma unroll
                for (int r = 0; r < 4; ++r) {
                    const int i = rbase + mt * 16 + kg * 4 + r;
                    rbias[r] = md ? ((const float*)bias)[i] : bf2f(((const bf16_t*)bias)[i]);
                }
            }
#pragma unroll
            for (int nt = 0; nt < 4; ++nt) {
                const int col = cbase + nt * 16 + lm;
                float cbias = 0.f;
                if (MODE == EPI_BIAS_COL)
                    cbias = md ? ((const float*)bias)[col] : bf2f(((const bf16_t*)bias)[col]);
#pragma unroll
                for (int r = 0; r < 4; ++r) {
                    const int row = rbase + mt * 16 + kg * 4 + r;
                    float vv = acc[p][mt][nt][r];
                    if (MODE == EPI_BIAS_ROW) vv += rbias[r];
                    if (MODE == EPI_BIAS_COL) vv += cbias;
                    if (MODE == EPI_SCALE)    vv *= scale;
                    const size_t off = (size_t)cOff + (size_t)z * sC + (size_t)row * 1024 + col;
                    if (DUALOUT && md) ((float*)C)[off] = vv;
                    else               ((bf16_t*)C)[off] = f2bf(vv);
                }
            }
        }
    }
}

// In-place chunked softmax + transpose on Y[zb][DM][DM] (bf16 internal).
__global__ void softmax_t_inplace(bf16_t* __restrict__ Y)
{
    const int b = blockIdx.z;
    int idx = blockIdx.x;           // 0..135
    int I = 0;
    while (idx >= 16 - I) { idx -= 16 - I; ++I; }
    const int J = I + idx;

    const int tid = threadIdx.x;
    const int r  = tid >> 2;
    const int cp = tid & 3;

    bf16_t* base = Y + ((size_t)b << 20);
    bf16_t* t0 = base + (size_t)(I * 64 + r) * DM + J * 64 + cp * 16;
    bf16_t* t1 = base + (size_t)(J * 64 + r) * DM + I * 64 + cp * 16;

    __shared__ bf16_t P0[64][72];
    __shared__ bf16_t P1[64][72];

    bf16x8 a0 = *(const bf16x8*)t0;
    bf16x8 a1 = *(const bf16x8*)(t0 + 8);
    bf16x8 c0v, c1v;
    if (J != I) { c0v = *(const bf16x8*)t1; c1v = *(const bf16x8*)(t1 + 8); }

    {
        float f[16];
#pragma unroll
        for (int j = 0; j < 8; ++j) f[j] = bf2f(a0[j]);
#pragma unroll
        for (int j = 0; j < 8; ++j) f[8 + j] = bf2f(a1[j]);
        float m = -1e30f;
#pragma unroll
        for (int j = 0; j < 16; ++j) m = fmaxf(m, f[j]);
        m = fmaxf(m, __shfl_xor(m, 1));
        m = fmaxf(m, __shfl_xor(m, 2));
        float s = 0.f;
#pragma unroll
        for (int j = 0; j < 16; ++j) { f[j] = __expf(f[j] - m); s += f[j]; }
        s += __shfl_xor(s, 1);
        s += __shfl_xor(s, 2);
        const float inv = 1.0f / s;
#pragma unroll
        for (int j = 0; j < 16; ++j) P0[cp * 16 + j][r] = f2bf(f[j] * inv);
    }
    if (J != I) {
        float f[16];
#pragma unroll
        for (int j = 0; j < 8; ++j) f[j] = bf2f(c0v[j]);
#pragma unroll
        for (int j = 0; j < 8; ++j) f[8 + j] = bf2f(c1v[j]);
        float m = -1e30f;
#pragma unroll
        for (int j = 0; j < 16; ++j) m = fmaxf(m, f[j]);
        m = fmaxf(m, __shfl_xor(m, 1));
        m = fmaxf(m, __shfl_xor(m, 2));
        float s = 0.f;
#pragma unroll
        for (int j = 0; j < 16; ++j) { f[j] = __expf(f[j] - m); s += f[j]; }
        s += __shfl_xor(s, 1);
        s += __shfl_xor(s, 2);
        const float inv = 1.0f / s;
#pragma unroll
        for (int j = 0; j < 16; ++j) P1[cp * 16 + j][r] = f2bf(f[j] * inv);
    }
    __syncthreads();

    bf16x8 w0, w1;
#pragma unroll
    for (int j = 0; j < 8; ++j) w0[j] = P0[r][cp * 16 + j];
#pragma unroll
    for (int j = 0; j < 8; ++j) w1[j] = P0[r][cp * 16 + 8 + j];
    *(bf16x8*)t1 = w0;
    *(bf16x8*)(t1 + 8) = w1;
    if (J != I) {
#pragma unroll
        for (int j = 0; j < 8; ++j) w0[j] = P1[r][cp * 16 + j];
#pragma unroll
        for (int j = 0; j < 8; ++j) w1[j] = P1[r][cp * 16 + 8 + j];
        *(bf16x8*)t0 = w0;
        *(bf16x8*)(t0 + 8) = w1;
    }
}

extern "C" void kernel_launch(void* const* d_in, const int* in_sizes, int n_in,
                              void* d_out, int out_size, void* d_ws, size_t ws_size,
                              hipStream_t stream)
{
    const void* x  = d_in[0];
    const void* Wq = d_in[1];
    const void* bq = d_in[2];
    const void* Wk = d_in[3];
    const void* bk = d_in[4];
    const void* Wv = d_in[5];
    const void* bv = d_in[6];

    // one-time: allow 128 KiB dynamic LDS on the gemm instantiations
    static bool attr_done = false;
    if (!attr_done) {
        hipFuncSetAttribute((const void*)gemm_nt8<EPI_BIAS_ROW, false>,
                            hipFuncAttributeMaxDynamicSharedMemorySize, 131072);
        hipFuncSetAttribute((const void*)gemm_nt8<EPI_BIAS_COL, false>,
                            hipFuncAttributeMaxDynamicSharedMemorySize, 131072);
        hipFuncSetAttribute((const void*)gemm_nt8<EPI_SCALE, false>,
                            hipFuncAttributeMaxDynamicSharedMemorySize, 131072);
        hipFuncSetAttribute((const void*)gemm_nt8<EPI_NONE, true>,
                            hipFuncAttributeMaxDynamicSharedMemorySize, 131072);
        attr_done = true;
    }

    // ws layout: [mode int | pad to 256] [Wt 6MB] [xb CB] [qt CB] [kt CB] [y CB]
    char* ws = (char*)d_ws;
    int* mode = (int*)ws;
    const size_t MB2 = (size_t)DM * DM * 2;
    const size_t hdr = 256;
    int CB = NB;
    while (CB > 1 && hdr + 3 * MB2 + 4 * (size_t)CB * MB2 > ws_size) CB >>= 1;

    bf16_t* Wt = (bf16_t*)(ws + hdr);
    bf16_t* xb = (bf16_t*)(ws + hdr + 3 * MB2);
    bf16_t* qt = xb + (size_t)CB * DM * DM;
    bf16_t* kt = qt + (size_t)CB * DM * DM;
    bf16_t* y  = kt + (size_t)CB * DM * DM;
    bf16_t* v  = qt;   // qt dead after QK^T; reuse for V

    detect_mode<<<1, 64, 0, stream>>>((const unsigned short*)x, mode);
    transpose3<<<dim3(16, 16, 3), 256, 0, stream>>>(Wq, Wk, Wv, Wt, mode);

    const long long msz = (long long)DM * DM;
    for (int c = 0; c < NB; c += CB) {
        const int zb = (NB - c < CB) ? (NB - c) : CB;
        const long long n8 = (long long)zb * msz / 8;
        convert_x<<<(int)((n8 + 255) / 256), 256, 0, stream>>>(x, xb, mode, (long long)c * msz, n8);

        const dim3 g8(4, 4, zb), blk8(512);
        // qt[b][d][s] = Wq^T x^T + bq (row bias)
        gemm_nt8<EPI_BIAS_ROW, false><<<g8, blk8, 131072, stream>>>(Wt, 0, xb, msz, qt, msz, 0, bq, mode, 1.f);
        // kt[b][e][s]
        gemm_nt8<EPI_BIAS_ROW, false><<<g8, blk8, 131072, stream>>>(Wt + msz, 0, xb, msz, kt, msz, 0, bk, mode, 1.f);
        // y[b][d][e] = qt . kt / 8
        gemm_nt8<EPI_SCALE, false><<<g8, blk8, 131072, stream>>>(qt, msz, kt, msz, y, msz, 0, nullptr, mode, 0.125f);
        // y <- softmax+transpose in place
        softmax_t_inplace<<<dim3(136, 1, zb), 256, 0, stream>>>(y);
        // v[b][s][d] = x Wv^T + bv (col bias) -> qt slab
        gemm_nt8<EPI_BIAS_COL, false><<<g8, blk8, 131072, stream>>>(xb, msz, Wt + 2 * msz, 0, v, msz, 0, bv, mode, 1.f);
        // out[b][s][e] = v . y   (dual-dtype output)
        gemm_nt8<EPI_NONE, true><<<g8, blk8, 131072, stream>>>(v, msz, y, msz, d_out, msz, (long long)c * msz, nullptr, mode, 1.f);
    }
}

// Round 4
// 671.223 us; speedup vs baseline: 1.1915x; 1.0062x over previous
//
#include <hip/hip_runtime.h>
#include <hip/hip_bf16.h>

// Problem: B=32, S=1024, D=1024, dm=1024, 16 heads x 64
#define DM 1024
#define NB 32

typedef __bf16 bf16_t;
typedef __attribute__((ext_vector_type(8))) __bf16 bf16x8;
typedef __attribute__((ext_vector_type(4))) float  f32x4;

// address-space typedefs for global_load_lds
typedef __attribute__((address_space(1))) void gas_void;
typedef __attribute__((address_space(3))) void las_void;

__device__ __forceinline__ void async_lds16(const bf16_t* g, bf16_t* l) {
    // 16B/lane direct global->LDS DMA. LDS dest must be wave-uniform base +
    // lane*16 (all call sites obey: lds byte = (i*512 + tid)*16).
    __builtin_amdgcn_global_load_lds((gas_void*)g, (las_void*)l, 16, 0, 0);
}

__device__ inline float bf2f(bf16_t v) {
    union { unsigned short s; __bf16 b; } u; u.b = v;
    union { unsigned int i; float f; } w; w.i = ((unsigned int)u.s) << 16;
    return w.f;
}
__device__ inline bf16_t f2bf(float f) {
    union { unsigned int i; float f; } w; w.f = f;
    unsigned int r = (w.i + 0x7FFFu + ((w.i >> 16) & 1u)) >> 16;
    union { unsigned short s; __bf16 b; } u; u.s = (unsigned short)r;
    return u.b;
}

enum EpiMode { EPI_NONE = 0, EPI_BIAS_ROW = 1, EPI_BIAS_COL = 2, EPI_SCALE = 3 };

// ---- dtype probe: mode=1 if x is fp32, mode=0 if bf16 ----
__global__ void detect_mode(const unsigned short* __restrict__ x, int* __restrict__ mode)
{
    if (threadIdx.x == 0 && blockIdx.x == 0) {
        int hits = 0;
        for (int i = 0; i < 2048; ++i) {
            unsigned e = (x[i] >> 7) & 0xFFu;
            hits += (e >= 0x8Du) ? 1 : 0;
        }
        *mode = (hits >= 16) ? 1 : 0;
    }
}

// ---- convert x (elements [off, off+n8*8)) to bf16 ----
__global__ void convert_x(const void* __restrict__ xin, bf16_t* __restrict__ xb,
                          const int* __restrict__ modep, long long off, long long n8)
{
    const long long i = (long long)blockIdx.x * blockDim.x + threadIdx.x;
    if (i >= n8) return;
    bf16x8 o;
    if (*modep) {
        const float* s = (const float*)xin + off + i * 8;
#pragma unroll
        for (int j = 0; j < 8; ++j) o[j] = f2bf(s[j]);
    } else {
        o = *(const bf16x8*)((const bf16_t*)xin + off + i * 8);
    }
    *(bf16x8*)(xb + i * 8) = o;
}

// ---- transpose the three weight matrices -> bf16 Wt[n][k] = W[k][n] ----
__global__ void transpose3(const void* __restrict__ Wq, const void* __restrict__ Wk,
                           const void* __restrict__ Wv, bf16_t* __restrict__ Wt,
                           const int* __restrict__ modep)
{
    const int md = *modep;
    const void* src = (blockIdx.z == 0) ? Wq : (blockIdx.z == 1) ? Wk : Wv;
    bf16_t* dst = Wt + (size_t)blockIdx.z * DM * DM;
    __shared__ bf16_t T[64][72];
    const int tid = threadIdx.x;
    const int r  = tid >> 2;   // 0..63
    const int cp = tid & 3;    // 16 elems each
    const int r0 = blockIdx.y * 64;  // k block
    const int c0 = blockIdx.x * 64;  // n block
    const size_t base = (size_t)(r0 + r) * DM + c0 + cp * 16;
    bf16_t tmp[16];
    if (md) {
        const float* s = (const float*)src + base;
#pragma unroll
        for (int j = 0; j < 16; ++j) tmp[j] = f2bf(s[j]);
    } else {
        const bf16_t* s = (const bf16_t*)src + base;
        bf16x8 a = *(const bf16x8*)s;
        bf16x8 b = *(const bf16x8*)(s + 8);
#pragma unroll
        for (int j = 0; j < 8; ++j) { tmp[j] = a[j]; tmp[8 + j] = b[j]; }
    }
#pragma unroll
    for (int j = 0; j < 16; ++j) T[cp * 16 + j][r] = tmp[j];
    __syncthreads();
    bf16_t* d = dst + (size_t)(c0 + r) * DM + r0 + cp * 16;
    bf16x8 w0, w1;
#pragma unroll
    for (int j = 0; j < 8; ++j) w0[j] = T[r][cp * 16 + j];
#pragma unroll
    for (int j = 0; j < 8; ++j) w1[j] = T[r][cp * 16 + 8 + j];
    *(bf16x8*)d = w0;
    *(bf16x8*)(d + 8) = w1;
}

// ============================================================================
// 256x256 NT gemm, 4-phase pipelined schedule (T2+T3+T4+T5).
// 512 threads = 8 waves; per K-tile (BK=64) 4 phases; phase p computes
// quadrant (row-half p&1, col-half p>>1), 16 MFMA 16x16x32.
// R4: FRAGMENT READS PIPELINED ONE PHASE AHEAD into disjoint register sets
// (af0/af1/bg0/bg1), so the pre-MFMA lgkm wait (compiler-counted) covers only
// reads issued a FULL PHASE earlier -> fresh reads drain under the MFMA.
//   read-for[p1]=s2->af1 @p0 body; read-for[p2]=s3->bg1 @p1 body;
//   read-for[p3]=none;  read-for[next p0]=s0',s1'->af0,bg0 @p3 body (buf^1).
// Slots: 0=A-h0, 1=B-h0, 2=A-h1, 3=B-h1. Stage slot p of tile t+1 @phase p.
// One barrier per phase (end), preceded by counted vmcnt publication:
//   p0-end vmcnt(2) publishes s3(t);  p1-end none;
//   p2-end vmcnt(2) publishes s0',s1';  p3-end vmcnt(2) publishes s2'.
// In-flight global_load_lds never drained to 0 in-loop (max 6 outstanding).
// Swizzle (T2): LDS linear (gload_lds constraint), global SOURCE kc^=(row&7),
// fragment reads apply the same XOR -> conflict-free (measured 0).
// ============================================================================
template <int MODE, bool DUALOUT>
__global__ __launch_bounds__(512, 2)
void gemm_nt8(const bf16_t* __restrict__ A, long long sA,
              const bf16_t* __restrict__ B, long long sB,
              void* __restrict__ C, long long sC, long long cOff,
              const void* __restrict__ bias, const int* __restrict__ modep,
              float scale)
{
    constexpr int K = 1024;
    constexpr int NT = K / 64;          // 16 K-tiles
    extern __shared__ bf16_t L[];       // 2*4*8192 bf16 = 128 KiB

    // ---- XCD-aware bijective swizzle (grid is 4 x 4 x z, nwg % 8 == 0) ----
    int bx, by, z;
    {
        const int nwg  = 16 * (int)gridDim.z;
        const int orig = (int)blockIdx.x + 4 * ((int)blockIdx.y + 4 * (int)blockIdx.z);
        const int nid  = (orig & 7) * (nwg >> 3) + (orig >> 3);
        bx = nid & 3; by = (nid >> 2) & 3; z = nid >> 4;
    }

    const bf16_t* Ab = A + (size_t)z * (size_t)sA;
    const bf16_t* Bb = B + (size_t)z * (size_t)sB;
    const int gm0 = by * 256, gn0 = bx * 256;

    const int tid  = threadIdx.x;
    const int lane = tid & 63;
    const int w    = tid >> 6;      // 0..7
    const int rb   = w >> 1;        // 0..3: 32-row band within each row-half
    const int cb   = w & 1;         // 0..1: 64-col band within each col-half
    const int lm   = lane & 15;
    const int kg   = lane >> 4;     // 0..3

    f32x4 acc[4][2][4];
#pragma unroll
    for (int p = 0; p < 4; ++p)
#pragma unroll
        for (int i = 0; i < 2; ++i)
#pragma unroll
            for (int j = 0; j < 4; ++j) acc[p][i][j] = (f32x4)0.0f;

    // fragment register sets (disjoint; pipelined reads never collide with
    // the phase consuming the other set)
    bf16x8 af0[2][2], af1[2][2], bg0[4][2], bg1[4][2];

    // stage slot s of K-tile kt into buffer b (2 x global_load_lds / thread)
    // slots: 0=A-h0, 1=B-h0, 2=A-h1, 3=B-h1
    auto stage = [&](int kt, int s, int b) {
        const bf16_t* P  = (s & 1) ? Bb : Ab;
        const int     g0 = (s & 1) ? gn0 : gm0;
        const int     h  = (s >= 2) ? 1 : 0;
        bf16_t* dst = L + (b * 4 + s) * 8192;
#pragma unroll
        for (int i = 0; i < 2; ++i) {
            const int ci  = i * 512 + tid;
            const int row = ci >> 3;
            const int kc  = (ci & 7) ^ (row & 7);   // pre-swizzled source
            async_lds16(P + (size_t)(g0 + h * 128 + row) * K + kt * 64 + kc * 8,
                        dst + ci * 8);
        }
    };

    // fragment read: row r (0..127) within a half-slot, 8-elem chunk kc (0..7)
    auto rdfrag = [&](int b, int s, int r, int kc) -> bf16x8 {
        const int byte = r * 128 + ((kc ^ (r & 7)) * 16);
        return *(const bf16x8*)((const char*)(L + (b * 4 + s) * 8192) + byte);
    };
    auto rdA = [&](int b, int s, bf16x8 (&dst)[2][2]) {
#pragma unroll
        for (int mt = 0; mt < 2; ++mt)
#pragma unroll
            for (int kk = 0; kk < 2; ++kk)
                dst[mt][kk] = rdfrag(b, s, rb * 32 + mt * 16 + lm, kk * 4 + kg);
    };
    auto rdB = [&](int b, int s, bf16x8 (&dst)[4][2]) {
#pragma unroll
        for (int nt = 0; nt < 4; ++nt)
#pragma unroll
            for (int kk = 0; kk < 2; ++kk)
                dst[nt][kk] = rdfrag(b, s, cb * 64 + nt * 16 + lm, kk * 4 + kg);
    };

#define MFMA_PHASE(P, AF, BG)                                                  \
    __builtin_amdgcn_s_setprio(1);                                             \
    _Pragma("unroll")                                                          \
    for (int kk = 0; kk < 2; ++kk)                                             \
        _Pragma("unroll")                                                      \
        for (int mt = 0; mt < 2; ++mt)                                         \
            _Pragma("unroll")                                                  \
            for (int nt = 0; nt < 4; ++nt)                                     \
                acc[P][mt][nt] = __builtin_amdgcn_mfma_f32_16x16x32_bf16(      \
                    AF[mt][kk], BG[nt][kk], acc[P][mt][nt], 0, 0, 0);          \
    __builtin_amdgcn_s_setprio(0);

    // ---- prologue: stage tile0, publish s0..s2, preload p0 fragments ----
#pragma unroll
    for (int s = 0; s < 4; ++s) stage(0, s, 0);
    asm volatile("s_waitcnt vmcnt(4)" ::: "memory");   // s0,s1 landed
    __builtin_amdgcn_s_barrier();                      // publish s0,s1
    rdA(0, 0, af0);                                    // p0 fragments
    rdB(0, 1, bg0);
    asm volatile("s_waitcnt vmcnt(2)" ::: "memory");   // s2 landed (slot3 in flight)
    __builtin_amdgcn_s_barrier();                      // publish s2

#pragma unroll 1
    for (int kt = 0; kt < NT; ++kt) {
        const int cur = kt & 1;
        const int nxt = cur ^ 1;
        const int nkt = (kt + 1 < NT) ? kt + 1 : 0;    // dummy re-stage on last

        // ---- phase 0: MFMA af0 x bg0 | read s2->af1 | stage slot0' ----
        rdA(cur, 2, af1);
        stage(nkt, 0, nxt);
        __builtin_amdgcn_sched_barrier(0);
        MFMA_PHASE(0, af0, bg0)
        __builtin_amdgcn_sched_barrier(0);
        asm volatile("s_waitcnt vmcnt(2)" ::: "memory");   // s3(t) landed
        __builtin_amdgcn_s_barrier();                      // publish s3

        // ---- phase 1: MFMA af1 x bg0 | read s3->bg1 | stage slot1' ----
        rdB(cur, 3, bg1);
        stage(nkt, 1, nxt);
        __builtin_amdgcn_sched_barrier(0);
        MFMA_PHASE(1, af1, bg0)
        __builtin_amdgcn_sched_barrier(0);
        __builtin_amdgcn_s_barrier();                      // no publication needed

        // ---- phase 2: MFMA af0 x bg1 | stage slot2' ----
        stage(nkt, 2, nxt);
        __builtin_amdgcn_sched_barrier(0);
        MFMA_PHASE(2, af0, bg1)
        __builtin_amdgcn_sched_barrier(0);
        asm volatile("s_waitcnt vmcnt(2)" ::: "memory");   // s0',s1' landed
        __builtin_amdgcn_s_barrier();                      // publish s0',s1'

        // ---- phase 3: MFMA af1 x bg1 | read s0'->af0, s1'->bg0 | stage slot3' ----
        rdA(nxt, 0, af0);
        rdB(nxt, 1, bg0);
        stage(nkt, 3, nxt);
        __builtin_amdgcn_sched_barrier(0);
        MFMA_PHASE(3, af1, bg1)
        __builtin_amdgcn_sched_barrier(0);
        asm volatile("s_waitcnt vmcnt(2)" ::: "memory");   // s2' landed
        __builtin_amdgcn_s_barrier();                      // publish s2'
    }
#undef MFMA_PHASE

    // ---- epilogue: C/D layout col=lane&15, row=kg*4+r (m89/m91-verified) ----
    // phase p = quadrant (row-half p&1, col-half p>>1)
    const int md = *modep;
#pragma unroll
    for (int p = 0; p < 4; ++p) {
        const int rbase = gm0 + (p & 1) * 128 + rb * 32;
        const int cbase = gn0 + (p >> 1) * 128 + cb * 64;
#pragma unroll
        for (int mt = 0; mt < 2; ++mt) {
            float rbias[4];
            if (MODE == EPI_BIAS_ROW) {
#pragma unroll
                for (int r = 0; r < 4; ++r) {
                    const int i = rbase + mt * 16 + kg * 4 + r;
                    rbias[r] = md ? ((const float*)bias)[i] : bf2f(((const bf16_t*)bias)[i]);
                }
            }
#pragma unroll
            for (int nt = 0; nt < 4; ++nt) {
                const int col = cbase + nt * 16 + lm;
                float cbias = 0.f;
                if (MODE == EPI_BIAS_COL)
                    cbias = md ? ((const float*)bias)[col] : bf2f(((const bf16_t*)bias)[col]);
#pragma unroll
                for (int r = 0; r < 4; ++r) {
                    const int row = rbase + mt * 16 + kg * 4 + r;
                    float vv = acc[p][mt][nt][r];
                    if (MODE == EPI_BIAS_ROW) vv += rbias[r];
                    if (MODE == EPI_BIAS_COL) vv += cbias;
                    if (MODE == EPI_SCALE)    vv *= scale;
                    const size_t off = (size_t)cOff + (size_t)z * sC + (size_t)row * 1024 + col;
                    if (DUALOUT && md) ((float*)C)[off] = vv;
                    else               ((bf16_t*)C)[off] = f2bf(vv);
                }
            }
        }
    }
}

// In-place chunked softmax + transpose on Y[zb][DM][DM] (bf16 internal).
__global__ void softmax_t_inplace(bf16_t* __restrict__ Y)
{
    const int b = blockIdx.z;
    int idx = blockIdx.x;           // 0..135
    int I = 0;
    while (idx >= 16 - I) { idx -= 16 - I; ++I; }
    const int J = I + idx;

    const int tid = threadIdx.x;
    const int r  = tid >> 2;
    const int cp = tid & 3;

    bf16_t* base = Y + ((size_t)b << 20);
    bf16_t* t0 = base + (size_t)(I * 64 + r) * DM + J * 64 + cp * 16;
    bf16_t* t1 = base + (size_t)(J * 64 + r) * DM + I * 64 + cp * 16;

    __shared__ bf16_t P0[64][72];
    __shared__ bf16_t P1[64][72];

    bf16x8 a0 = *(const bf16x8*)t0;
    bf16x8 a1 = *(const bf16x8*)(t0 + 8);
    bf16x8 c0v, c1v;
    if (J != I) { c0v = *(const bf16x8*)t1; c1v = *(const bf16x8*)(t1 + 8); }

    {
        float f[16];
#pragma unroll
        for (int j = 0; j < 8; ++j) f[j] = bf2f(a0[j]);
#pragma unroll
        for (int j = 0; j < 8; ++j) f[8 + j] = bf2f(a1[j]);
        float m = -1e30f;
#pragma unroll
        for (int j = 0; j < 16; ++j) m = fmaxf(m, f[j]);
        m = fmaxf(m, __shfl_xor(m, 1));
        m = fmaxf(m, __shfl_xor(m, 2));
        float s = 0.f;
#pragma unroll
        for (int j = 0; j < 16; ++j) { f[j] = __expf(f[j] - m); s += f[j]; }
        s += __shfl_xor(s, 1);
        s += __shfl_xor(s, 2);
        const float inv = 1.0f / s;
#pragma unroll
        for (int j = 0; j < 16; ++j) P0[cp * 16 + j][r] = f2bf(f[j] * inv);
    }
    if (J != I) {
        float f[16];
#pragma unroll
        for (int j = 0; j < 8; ++j) f[j] = bf2f(c0v[j]);
#pragma unroll
        for (int j = 0; j < 8; ++j) f[8 + j] = bf2f(c1v[j]);
        float m = -1e30f;
#pragma unroll
        for (int j = 0; j < 16; ++j) m = fmaxf(m, f[j]);
        m = fmaxf(m, __shfl_xor(m, 1));
        m = fmaxf(m, __shfl_xor(m, 2));
        float s = 0.f;
#pragma unroll
        for (int j = 0; j < 16; ++j) { f[j] = __expf(f[j] - m); s += f[j]; }
        s += __shfl_xor(s, 1);
        s += __shfl_xor(s, 2);
        const float inv = 1.0f / s;
#pragma unroll
        for (int j = 0; j < 16; ++j) P1[cp * 16 + j][r] = f2bf(f[j] * inv);
    }
    __syncthreads();

    bf16x8 w0, w1;
#pragma unroll
    for (int j = 0; j < 8; ++j) w0[j] = P0[r][cp * 16 + j];
#pragma unroll
    for (int j = 0; j < 8; ++j) w1[j] = P0[r][cp * 16 + 8 + j];
    *(bf16x8*)t1 = w0;
    *(bf16x8*)(t1 + 8) = w1;
    if (J != I) {
#pragma unroll
        for (int j = 0; j < 8; ++j) w0[j] = P1[r][cp * 16 + j];
#pragma unroll
        for (int j = 0; j < 8; ++j) w1[j] = P1[r][cp * 16 + 8 + j];
        *(bf16x8*)t0 = w0;
        *(bf16x8*)(t0 + 8) = w1;
    }
}

extern "C" void kernel_launch(void* const* d_in, const int* in_sizes, int n_in,
                              void* d_out, int out_size, void* d_ws, size_t ws_size,
                              hipStream_t stream)
{
    const void* x  = d_in[0];
    const void* Wq = d_in[1];
    const void* bq = d_in[2];
    const void* Wk = d_in[3];
    const void* bk = d_in[4];
    const void* Wv = d_in[5];
    const void* bv = d_in[6];

    // one-time: allow 128 KiB dynamic LDS on the gemm instantiations
    static bool attr_done = false;
    if (!attr_done) {
        hipFuncSetAttribute((const void*)gemm_nt8<EPI_BIAS_ROW, false>,
                            hipFuncAttributeMaxDynamicSharedMemorySize, 131072);
        hipFuncSetAttribute((const void*)gemm_nt8<EPI_BIAS_COL, false>,
                            hipFuncAttributeMaxDynamicSharedMemorySize, 131072);
        hipFuncSetAttribute((const void*)gemm_nt8<EPI_SCALE, false>,
                            hipFuncAttributeMaxDynamicSharedMemorySize, 131072);
        hipFuncSetAttribute((const void*)gemm_nt8<EPI_NONE, true>,
                            hipFuncAttributeMaxDynamicSharedMemorySize, 131072);
        attr_done = true;
    }

    // ws layout: [mode int | pad to 256] [Wt 6MB] [xb CB] [qt CB] [kt CB] [y CB]
    char* ws = (char*)d_ws;
    int* mode = (int*)ws;
    const size_t MB2 = (size_t)DM * DM * 2;
    const size_t hdr = 256;
    int CB = NB;
    while (CB > 1 && hdr + 3 * MB2 + 4 * (size_t)CB * MB2 > ws_size) CB >>= 1;

    bf16_t* Wt = (bf16_t*)(ws + hdr);
    bf16_t* xb = (bf16_t*)(ws + hdr + 3 * MB2);
    bf16_t* qt = xb + (size_t)CB * DM * DM;
    bf16_t* kt = qt + (size_t)CB * DM * DM;
    bf16_t* y  = kt + (size_t)CB * DM * DM;
    bf16_t* v  = qt;   // qt dead after QK^T; reuse for V

    detect_mode<<<1, 64, 0, stream>>>((const unsigned short*)x, mode);
    transpose3<<<dim3(16, 16, 3), 256, 0, stream>>>(Wq, Wk, Wv, Wt, mode);

    const long long msz = (long long)DM * DM;
    for (int c = 0; c < NB; c += CB) {
        const int zb = (NB - c < CB) ? (NB - c) : CB;
        const long long n8 = (long long)zb * msz / 8;
        convert_x<<<(int)((n8 + 255) / 256), 256, 0, stream>>>(x, xb, mode, (long long)c * msz, n8);

        const dim3 g8(4, 4, zb), blk8(512);
        // qt[b][d][s] = Wq^T x^T + bq (row bias)
        gemm_nt8<EPI_BIAS_ROW, false><<<g8, blk8, 131072, stream>>>(Wt, 0, xb, msz, qt, msz, 0, bq, mode, 1.f);
        // kt[b][e][s]
        gemm_nt8<EPI_BIAS_ROW, false><<<g8, blk8, 131072, stream>>>(Wt + msz, 0, xb, msz, kt, msz, 0, bk, mode, 1.f);
        // y[b][d][e] = qt . kt / 8
        gemm_nt8<EPI_SCALE, false><<<g8, blk8, 131072, stream>>>(qt, msz, kt, msz, y, msz, 0, nullptr, mode, 0.125f);
        // y <- softmax+transpose in place
        softmax_t_inplace<<<dim3(136, 1, zb), 256, 0, stream>>>(y);
        // v[b][s][d] = x Wv^T + bv (col bias) -> qt slab
        gemm_nt8<EPI_BIAS_COL, false><<<g8, blk8, 131072, stream>>>(xb, msz, Wt + 2 * msz, 0, v, msz, 0, bv, mode, 1.f);
        // out[b][s][e] = v . y   (dual-dtype output)
        gemm_nt8<EPI_NONE, true><<<g8, blk8, 131072, stream>>>(v, msz, y, msz, d_out, msz, (long long)c * msz, nullptr, mode, 1.f);
    }
}